// Round 5
// baseline (3777.825 us; speedup 1.0000x reference)
//
#include <hip/hip_runtime.h>
#include <math.h>
#include <stdint.h>

// ---- problem dims ----
constexpr int Bsz = 512, Kf = 36, Dd = 2048, Aa = 512, Hh = 512, Em = 300;
constexpr int Vv = 10000, TSTEPS = 19, BOS = 1;
constexpr int K1 = 832;          // padded Em+Hh (812 -> 832)
constexpr int K2 = 1536;         // h1|ctx|h2
constexpr int VvP = 10112;       // vocab rows padded (mult of 128)
constexpr float SPLIT_S  = 2048.0f;
constexpr float SPLIT_IS = 1.0f / 2048.0f;

#define CDIV(a,b) (((a)+(b)-1)/(b))

typedef _Float16 f16x8 __attribute__((ext_vector_type(8)));
typedef float    f32x4 __attribute__((ext_vector_type(4)));

typedef const unsigned int GU __attribute__((address_space(1)));
typedef unsigned int       LU __attribute__((address_space(3)));

__device__ __forceinline__ void gload16(const void* g, void* l) {
    __builtin_amdgcn_global_load_lds((GU*)g, (LU*)l, 16, 0, 0);
}

template<int N> __device__ __forceinline__ void wait_vm() {
    if constexpr (N == 0)       asm volatile("s_waitcnt vmcnt(0)" ::: "memory");
    else if constexpr (N == 4)  asm volatile("s_waitcnt vmcnt(4)" ::: "memory");
    else if constexpr (N == 6)  asm volatile("s_waitcnt vmcnt(6)" ::: "memory");
    else if constexpr (N == 8)  asm volatile("s_waitcnt vmcnt(8)" ::: "memory");
    else static_assert(N == 0, "unsupported vmcnt literal");
}
#define WAIT_LGKM asm volatile("s_waitcnt lgkmcnt(0)" ::: "memory")
#define SB0 __builtin_amdgcn_sched_barrier(0)
#define BAR __builtin_amdgcn_s_barrier()

__device__ __forceinline__ float sigm(float v) { return 1.0f / (1.0f + expf(-v)); }

__device__ __forceinline__ void wsplit(_Float16* __restrict__ hi, _Float16* __restrict__ lo,
                                       size_t idx, float v) {
    _Float16 h = (_Float16)v;
    hi[idx] = h;
    lo[idx] = (_Float16)((v - (float)h) * SPLIT_S);
}

// ============================================================
// Split-fp16 MFMA GEMM, double-buffered LDS + counted-vmcnt prefetch,
// XCD-bijective block swizzle (grid must be a multiple of 8 blocks).
//   C[M,N] = A[M,K] @ B[N,K]^T (+bias1+bias2+addC)
// NFAST: consecutive logical blocks share the A m-tile (A-reuse in L2);
// else they share the B n-tile (B-reuse in L2).
// ============================================================
template<int BM, int BN, int BK, bool AF32, bool NFAST, int OCC>
__global__ __launch_bounds__(256, OCC)
void gemm_sp(const float* __restrict__ Af,
             const _Float16* __restrict__ Ahi, const _Float16* __restrict__ Alo, int lda,
             const _Float16* __restrict__ Bhi, const _Float16* __restrict__ Blo, int ldb,
             float* __restrict__ C, int ldc, int N, int K,
             const float* __restrict__ bias1, const float* __restrict__ bias2,
             const float* __restrict__ addC, int gxn)
{
    constexpr int WM = BM / 2, WN = BN / 2;
    constexpr int MF = WM / 16, NF = WN / 16;
    constexpr int PA  = BK / 8;
    constexpr int PSA = BM * 8 + 8;
    constexpr int PSB = BN * 8 + 8;
    constexpr int SZA = PA * PSA, SZB = PA * PSB;
    constexpr int OAH = 0, OAL = SZA, OBH = 2 * SZA, OBL = 2 * SZA + SZB;
    constexpr int BUF = 2 * SZA + 2 * SZB;
    constexpr int NCHA = BM * BK / 2048;
    constexpr int NCHB = BN * BK / 2048;
    constexpr int LW = 2 * NCHA + 2 * NCHB;
    __shared__ _Float16 sm[2 * BUF];

    // ---- XCD-bijective swizzle ----
    const int nwg = gridDim.x;
    const int cpx = nwg >> 3;
    const int orig = blockIdx.x;
    const int lid = (orig & 7) * cpx + (orig >> 3);
    int mt, nt;
    if (NFAST) { nt = lid % gxn; mt = lid / gxn; }
    else       { const int gym = nwg / gxn; mt = lid % gym; nt = lid / gym; }
    const int m0 = mt * BM, n0 = nt * BN;

    const int t    = threadIdx.x;
    const int lane = t & 63;
    const int w    = t >> 6;
    const int wr   = w >> 1, wc = w & 1;
    const int l15  = lane & 15, l4 = lane >> 4;

    f32x4 acch[MF][NF];
    f32x4 accm[MF][NF];
    #pragma unroll
    for (int m = 0; m < MF; ++m)
        #pragma unroll
        for (int n = 0; n < NF; ++n) {
            acch[m][n] = (f32x4){0.f, 0.f, 0.f, 0.f};
            accm[m][n] = (f32x4){0.f, 0.f, 0.f, 0.f};
        }

    const int nkt = K / BK;

    auto stageB = [&](int bufo, int kt) {
        #pragma unroll
        for (int i = 0; i < NCHB; ++i) {
            const int q  = i * 256 + t;
            const int p  = q / BN, r = q % BN;
            const int qw = i * 256 + (t & ~63);
            const int pu = qw / BN, ru = qw % BN;
            const size_t goff = (size_t)(n0 + r) * ldb + kt * BK + p * 8;
            gload16(Bhi + goff, &sm[bufo + OBH + pu * PSB + ru * 8]);
            gload16(Blo + goff, &sm[bufo + OBL + pu * PSB + ru * 8]);
        }
    };
    auto stageA16 = [&](int bufo, int kt) {
        #pragma unroll
        for (int i = 0; i < NCHA; ++i) {
            const int q  = i * 256 + t;
            const int p  = q / BM, r = q % BM;
            const int qw = i * 256 + (t & ~63);
            const int pu = qw / BM, ru = qw % BM;
            const size_t goff = (size_t)(m0 + r) * lda + kt * BK + p * 8;
            gload16(Ahi + goff, &sm[bufo + OAH + pu * PSA + ru * 8]);
            gload16(Alo + goff, &sm[bufo + OAL + pu * PSA + ru * 8]);
        }
    };
    auto issueA = [&](float4 (&rd)[NCHA][2], int kt) {
        #pragma unroll
        for (int i = 0; i < NCHA; ++i) {
            const int q = i * 256 + t;
            const int p = q / BM, r = q % BM;
            const float* src = Af + (size_t)(m0 + r) * lda + kt * BK + p * 8;
            rd[i][0] = *(const float4*)src;
            rd[i][1] = *(const float4*)(src + 4);
        }
    };
    auto writeA = [&](int bufo, float4 (&rd)[NCHA][2]) {
        #pragma unroll
        for (int i = 0; i < NCHA; ++i) {
            const int q = i * 256 + t;
            const int p = q / BM, r = q % BM;
            const float f[8] = {rd[i][0].x, rd[i][0].y, rd[i][0].z, rd[i][0].w,
                                rd[i][1].x, rd[i][1].y, rd[i][1].z, rd[i][1].w};
            f16x8 hi, lo;
            #pragma unroll
            for (int j = 0; j < 8; ++j) {
                _Float16 h = (_Float16)f[j];
                hi[j] = h;
                lo[j] = (_Float16)((f[j] - (float)h) * SPLIT_S);
            }
            *(f16x8*)&sm[bufo + OAH + p * PSA + r * 8] = hi;
            *(f16x8*)&sm[bufo + OAL + p * PSA + r * 8] = lo;
        }
    };
    auto compute = [&](int bufo) {
        #pragma unroll
        for (int s = 0; s < BK / 32; ++s) {
            f16x8 ah[MF], al[MF], bh[NF], bl[NF];
            const int pl = s * 4 + l4;
            #pragma unroll
            for (int m = 0; m < MF; ++m) {
                const int row = wr * WM + m * 16 + l15;
                ah[m] = *(const f16x8*)&sm[bufo + OAH + pl * PSA + row * 8];
                al[m] = *(const f16x8*)&sm[bufo + OAL + pl * PSA + row * 8];
            }
            #pragma unroll
            for (int n = 0; n < NF; ++n) {
                const int row = wc * WN + n * 16 + l15;
                bh[n] = *(const f16x8*)&sm[bufo + OBH + pl * PSB + row * 8];
                bl[n] = *(const f16x8*)&sm[bufo + OBL + pl * PSB + row * 8];
            }
            #pragma unroll
            for (int m = 0; m < MF; ++m)
                #pragma unroll
                for (int n = 0; n < NF; ++n) {
                    acch[m][n] = __builtin_amdgcn_mfma_f32_16x16x32_f16(ah[m], bh[n], acch[m][n], 0, 0, 0);
                    accm[m][n] = __builtin_amdgcn_mfma_f32_16x16x32_f16(ah[m], bl[n], accm[m][n], 0, 0, 0);
                    accm[m][n] = __builtin_amdgcn_mfma_f32_16x16x32_f16(al[m], bh[n], accm[m][n], 0, 0, 0);
                }
        }
    };

    if constexpr (AF32) {
        // K/BK even at all AF32 call sites.
        float4 rA[NCHA][2], rB[NCHA][2];
        issueA(rA, 0); stageB(0, 0);
        for (int kt = 0; kt < nkt; kt += 2) {
            issueA(rB, kt + 1); stageB(BUF, kt + 1);
            wait_vm<LW>(); SB0;
            writeA(0, rA);
            WAIT_LGKM; SB0;
            BAR; SB0;
            compute(0);
            SB0; WAIT_LGKM; BAR; SB0;
            if (kt + 2 < nkt) { issueA(rA, kt + 2); stageB(0, kt + 2); wait_vm<LW>(); }
            else              { wait_vm<0>(); }
            SB0;
            writeA(BUF, rB);
            WAIT_LGKM; SB0;
            BAR; SB0;
            compute(BUF);
            SB0; WAIT_LGKM; BAR; SB0;
        }
    } else {
        stageA16(0, 0); stageB(0, 0);
        for (int kt = 0; kt < nkt; ++kt) {
            const int bufc = (kt & 1) ? BUF : 0;
            const int bufn = BUF - bufc;
            if (kt + 1 < nkt) { stageA16(bufn, kt + 1); stageB(bufn, kt + 1); wait_vm<LW>(); }
            else              { wait_vm<0>(); }
            SB0;
            BAR; SB0;
            compute(bufc);
            SB0; WAIT_LGKM; BAR; SB0;
        }
    }

    // ---- epilogue ----
    #pragma unroll
    for (int m = 0; m < MF; ++m) {
        const int rowb = m0 + wr * WM + m * 16 + l4 * 4;
        #pragma unroll
        for (int n = 0; n < NF; ++n) {
            const int col = n0 + wc * WN + n * 16 + l15;
            if (col < N) {
                float bb = 0.f;
                if (bias1) bb += bias1[col];
                if (bias2) bb += bias2[col];
                #pragma unroll
                for (int r = 0; r < 4; ++r) {
                    const size_t idx = (size_t)(rowb + r) * ldc + col;
                    float v = acch[m][n][r] + accm[m][n][r] * SPLIT_IS + bb;
                    if (addC) v += addC[idx];
                    C[idx] = v;
                }
            }
        }
    }
}

// ============================================================
// weight split-convert
// ============================================================
__global__ __launch_bounds__(256)
void split_convert(const float* __restrict__ src, int srcld, int validR,
                   _Float16* __restrict__ dhi, _Float16* __restrict__ dlo,
                   int dstld, int coloff, int R, int C)
{
    const int total = R * C;
    for (int i = blockIdx.x * 256 + threadIdx.x; i < total; i += gridDim.x * 256) {
        const int r = i / C, c = i % C;
        const float v = (r < validR) ? src[(size_t)r * srcld + c] : 0.f;
        wsplit(dhi, dlo, (size_t)r * dstld + coloff + c, v);
    }
}

// transpose Wa1[:, :H] -> WahT [H][A] fp32
__global__ __launch_bounds__(256)
void transpose_wah(const float* __restrict__ Wa1, float* __restrict__ WahT)
{
    const int i = blockIdx.x * 256 + threadIdx.x;
    if (i < Aa * Hh) {
        const int a = i / Hh, h = i % Hh;
        WahT[(size_t)h * Aa + a] = Wa1[(size_t)a * (Hh + Aa) + h];
    }
}

__global__ __launch_bounds__(256)
void init_kernel(_Float16* __restrict__ a1h, _Float16* __restrict__ a1l,
                 _Float16* __restrict__ a2h, _Float16* __restrict__ a2l,
                 float* __restrict__ c1, float* __restrict__ c2,
                 const float* __restrict__ E)
{
    const int idx = blockIdx.x * 256 + threadIdx.x;   // grid covers 512*1536
    if (idx < Bsz * K1) {
        const int col = idx % K1;
        const float v = (col < Em) ? E[(size_t)BOS * Em + col] : 0.f;
        wsplit(a1h, a1l, idx, v);
    }
    if (idx < Bsz * K2) wsplit(a2h, a2l, idx, 0.f);
    if (idx < Bsz * Hh) { c1[idx] = 0.f; c2[idx] = 0.f; }
}

// f_mean (fp32 + split pair)
__global__ __launch_bounds__(256)
void fmean_kernel(const float* __restrict__ f_att, float* __restrict__ f_mean,
                  _Float16* __restrict__ fmh, _Float16* __restrict__ fml)
{
    const int b = blockIdx.x;
    for (int a = threadIdx.x; a < Aa; a += 256) {
        float s = 0.f;
        for (int k = 0; k < Kf; ++k) s += f_att[((size_t)b * Kf + k) * Aa + a];
        const float v = s * (1.0f / 36.0f);
        f_mean[(size_t)b * Aa + a] = v;
        wsplit(fmh, fml, (size_t)b * Aa + a, v);
    }
}

// LSTM cell elementwise; h written as fp16 split pair(s).
__global__ __launch_bounds__(256)
void lstm_cell_kernel(const float* __restrict__ g, float* __restrict__ c,
                      _Float16* __restrict__ hhi, _Float16* __restrict__ hlo,
                      int hld, int hoff,
                      _Float16* __restrict__ h2hi, _Float16* __restrict__ h2lo,
                      int h2ld, int h2off)
{
    const int idx = blockIdx.x * 256 + threadIdx.x;   // < B*H
    const int b = idx >> 9, h = idx & 511;
    const float* gb = g + (size_t)b * 2048;
    const float gi = gb[h], gf = gb[512 + h], gc = gb[1024 + h], go = gb[1536 + h];
    const float cv = sigm(gf) * c[idx] + sigm(gi) * tanhf(gc);
    c[idx] = cv;
    const float hv = sigm(go) * tanhf(cv);
    wsplit(hhi, hlo, (size_t)b * hld + hoff + h, hv);
    if (h2hi) wsplit(h2hi, h2lo, (size_t)b * h2ld + h2off + h, hv);
}

// Fused attention: q matvec (h1 @ Wa1h^T via transposed weights), e scores,
// softmax over k, ctx -> A2 cols [512,1024). One block per b.
__global__ __launch_bounds__(256)
void attn_fused(const float* __restrict__ att_f,
                const _Float16* __restrict__ a2hin, const _Float16* __restrict__ a2lin,
                const float* __restrict__ WahT,
                const float* __restrict__ wa2, const float* __restrict__ ba2,
                const float* __restrict__ f_att,
                _Float16* __restrict__ a2h, _Float16* __restrict__ a2l)
{
    const int b = blockIdx.x, tid = threadIdx.x;
    const int w = tid >> 6, lane = tid & 63;
    __shared__ float sh1[Hh];
    __shared__ float sq[Aa];
    __shared__ float se[Kf];
    __shared__ float wk[Kf];
    // reconstruct h1 from split pair (exact to 2^-22)
    for (int h = tid; h < Hh; h += 256)
        sh1[h] = (float)a2hin[(size_t)b * K2 + h] + (float)a2lin[(size_t)b * K2 + h] * SPLIT_IS;
    __syncthreads();
    // q[a] = sum_h h1[h] * WahT[h][a]
    for (int a = tid; a < Aa; a += 256) {
        float acc = 0.f;
        for (int h = 0; h < Hh; ++h)
            acc = fmaf(sh1[h], WahT[(size_t)h * Aa + a], acc);
        sq[a] = acc;
    }
    __syncthreads();
    for (int k = w; k < Kf; k += 4) {
        const float* pf = att_f + ((size_t)b * Kf + k) * Aa;
        float s = 0.f;
        #pragma unroll
        for (int j = 0; j < Aa; j += 64) {
            const int a = j + lane;
            s += tanhf(pf[a] + sq[a]) * wa2[a];
        }
        #pragma unroll
        for (int off = 32; off; off >>= 1) s += __shfl_down(s, off);
        if (lane == 0) se[k] = s + ba2[0];
    }
    __syncthreads();
    if (tid < Kf) {
        float mx = -INFINITY;
        for (int k = 0; k < Kf; ++k) mx = fmaxf(mx, se[k]);
        float ssum = 0.f;
        for (int k = 0; k < Kf; ++k) ssum += expf(se[k] - mx);
        wk[tid] = expf(se[tid] - mx) / ssum;
    }
    __syncthreads();
    for (int a = tid; a < Aa; a += 256) {
        float acc = 0.f;
        for (int k = 0; k < Kf; ++k)
            acc = fmaf(wk[k], f_att[((size_t)b * Kf + k) * Aa + a], acc);
        wsplit(a2h, a2l, (size_t)b * K2 + Hh + a, acc);
    }
}

// argmax over vocab (first-index tie-break) + embed gather -> A1 split cols [0,300)
__global__ __launch_bounds__(256)
void argmax_embed_kernel(const float* __restrict__ logits, const float* __restrict__ E,
                         _Float16* __restrict__ a1h, _Float16* __restrict__ a1l,
                         int* __restrict__ out, int t)
{
    const int b = blockIdx.x;
    const int tid = threadIdx.x;
    float best = -INFINITY;
    int bi = Vv;
    for (int j = tid; j < Vv; j += 256) {
        const float v = logits[(size_t)b * Vv + j];
        if (v > best) { best = v; bi = j; }
    }
    __shared__ float sv[256];
    __shared__ int   si[256];
    sv[tid] = best; si[tid] = bi;
    __syncthreads();
    for (int s = 128; s > 0; s >>= 1) {
        if (tid < s) {
            const float v2 = sv[tid + s];
            const int   i2 = si[tid + s];
            if (v2 > sv[tid] || (v2 == sv[tid] && i2 < si[tid])) { sv[tid] = v2; si[tid] = i2; }
        }
        __syncthreads();
    }
    const int idx = si[0];
    if (tid == 0) out[(size_t)b * TSTEPS + t] = idx;
    for (int d = tid; d < Em; d += 256)
        wsplit(a1h, a1l, (size_t)b * K1 + d, E[(size_t)idx * Em + d]);
}

// ============================================================
// host side
// ============================================================
static inline void conv(hipStream_t s, const float* src, int srcld, int validR,
                        _Float16* dhi, _Float16* dlo, int dstld, int coloff, int R, int C)
{
    int blocks = CDIV(R * C, 256); if (blocks > 2048) blocks = 2048;
    split_convert<<<dim3(blocks), dim3(256), 0, s>>>(src, srcld, validR, dhi, dlo, dstld, coloff, R, C);
}

extern "C" void kernel_launch(void* const* d_in, const int* in_sizes, int n_in,
                              void* d_out, int out_size, void* d_ws, size_t ws_size,
                              hipStream_t stream)
{
    const float* feats = (const float*)d_in[0];
    const float* Wp    = (const float*)d_in[1];
    const float* bp    = (const float*)d_in[2];
    const float* E     = (const float*)d_in[3];
    const float* Wih1  = (const float*)d_in[4];
    const float* Whh1  = (const float*)d_in[5];
    const float* bih1  = (const float*)d_in[6];
    const float* bhh1  = (const float*)d_in[7];
    const float* Wih2  = (const float*)d_in[8];
    const float* Whh2  = (const float*)d_in[9];
    const float* bih2  = (const float*)d_in[10];
    const float* bhh2  = (const float*)d_in[11];
    const float* Wa1   = (const float*)d_in[12];
    const float* ba1   = (const float*)d_in[13];
    const float* wa2   = (const float*)d_in[14];
    const float* ba2   = (const float*)d_in[15];
    const float* Wo    = (const float*)d_in[16];
    const float* bo    = (const float*)d_in[17];
    int* out = (int*)d_out;
    (void)in_sizes; (void)n_in; (void)out_size; (void)ws_size;

    uint8_t* w = (uint8_t*)d_ws;
    size_t off = 0;
    auto alloc = [&](size_t bytes) { void* p = w + off; off = (off + bytes + 255) & ~(size_t)255; return p; };

    float*     f_att  = (float*)alloc(18432ull * 512 * 4);
    float*     att_f  = (float*)alloc(18432ull * 512 * 4);
    float*     f_mean = (float*)alloc(512ull * 512 * 4);
    _Float16*  fmh    = (_Float16*)alloc(512ull * 512 * 2);
    _Float16*  fml    = (_Float16*)alloc(512ull * 512 * 2);
    _Float16*  wph    = (_Float16*)alloc(512ull * 2048 * 2);
    _Float16*  wpl    = (_Float16*)alloc(512ull * 2048 * 2);
    _Float16*  w1ph   = (_Float16*)alloc(2048ull * K1 * 2);
    _Float16*  w1pl   = (_Float16*)alloc(2048ull * K1 * 2);
    _Float16*  w1ch   = (_Float16*)alloc(2048ull * 512 * 2);
    _Float16*  w1cl   = (_Float16*)alloc(2048ull * 512 * 2);
    _Float16*  w2ph   = (_Float16*)alloc(2048ull * K2 * 2);
    _Float16*  w2pl   = (_Float16*)alloc(2048ull * K2 * 2);
    float*     WahT   = (float*)alloc(512ull * 512 * 4);
    _Float16*  wafh   = (_Float16*)alloc(512ull * 512 * 2);
    _Float16*  wafl   = (_Float16*)alloc(512ull * 512 * 2);
    _Float16*  woh    = (_Float16*)alloc((size_t)VvP * 512 * 2);
    _Float16*  wol    = (_Float16*)alloc((size_t)VvP * 512 * 2);
    float*     g1c    = (float*)alloc(512ull * 2048 * 4);
    _Float16*  a1h    = (_Float16*)alloc(512ull * K1 * 2);
    _Float16*  a1l    = (_Float16*)alloc(512ull * K1 * 2);
    _Float16*  a2h    = (_Float16*)alloc(512ull * K2 * 2);
    _Float16*  a2l    = (_Float16*)alloc(512ull * K2 * 2);
    float*     c1     = (float*)alloc(512ull * 512 * 4);
    float*     c2     = (float*)alloc(512ull * 512 * 4);
    float*     gbuf   = (float*)alloc(512ull * 2048 * 4);
    float*     logits = (float*)alloc(512ull * Vv * 4);

    // ---- weight conversions ----
    conv(stream, Wp,          Dd,      512,   wph,  wpl,  2048, 0,    512,  2048);
    conv(stream, Wih1,        Em + Aa, 2048,  w1ph, w1pl, K1,   0,    2048, Em);
    conv(stream, Whh1,        Hh,      2048,  w1ph, w1pl, K1,   Em,   2048, 512);
    conv(stream, Wih1,        Em + Aa, 0,     w1ph, w1pl, K1,   812,  2048, 20);   // zero pad cols
    conv(stream, Wih1 + Em,   Em + Aa, 2048,  w1ch, w1cl, 512,  0,    2048, 512);
    conv(stream, Wih2,        Hh + Aa, 2048,  w2ph, w2pl, K2,   0,    2048, 1024);
    conv(stream, Whh2,        Hh,      2048,  w2ph, w2pl, K2,   1024, 2048, 512);
    transpose_wah<<<dim3(1024), dim3(256), 0, stream>>>(Wa1, WahT);
    conv(stream, Wa1 + Hh,    Hh + Aa, 512,   wafh, wafl, 512,  0,    512,  512);
    conv(stream, Wo,          Hh,      Vv,    woh,  wol,  512,  0,    VvP,  512);

    init_kernel<<<dim3(CDIV(Bsz * K2, 256)), dim3(256), 0, stream>>>(a1h, a1l, a2h, a2l, c1, c2, E);

    // ---- precompute GEMMs ----
    // f_att = feats @ Wp^T + bp   (M=18432 N=512 K=2048; 144x8 tiles, NFAST)
    gemm_sp<128, 64, 32, true, true, 2><<<dim3(1152), 256, 0, stream>>>(
        feats, nullptr, nullptr, Dd, wph, wpl, 2048, f_att, 512, 512, 2048, bp, nullptr, nullptr, 8);
    fmean_kernel<<<dim3(Bsz), dim3(256), 0, stream>>>(f_att, f_mean, fmh, fml);
    // g1c = f_mean @ Wih1[:,Em:]^T + bih1 + bhh1   (512 x 2048, K=512; 8x32)
    gemm_sp<64, 64, 32, false, false, 4><<<dim3(256), 256, 0, stream>>>(
        nullptr, fmh, fml, 512, w1ch, w1cl, 512, g1c, 2048, 2048, 512, bih1, bhh1, nullptr, 32);
    // att_f = f_att @ Wa1[:,H:]^T + ba1   (18432 x 512, K=512; NFAST)
    gemm_sp<128, 64, 32, true, true, 2><<<dim3(1152), 256, 0, stream>>>(
        f_att, nullptr, nullptr, 512, wafh, wafl, 512, att_f, 512, 512, 512, ba1, nullptr, nullptr, 8);

    // ---- decode loop ----
    for (int t = 0; t < TSTEPS; ++t) {
        // g1 = A1 @ W1p^T + g1c   (512 x 2048, K=832)
        gemm_sp<64, 64, 32, false, false, 4><<<dim3(256), 256, 0, stream>>>(
            nullptr, a1h, a1l, K1, w1ph, w1pl, K1, gbuf, 2048, 2048, K1, nullptr, nullptr, g1c, 32);
        lstm_cell_kernel<<<dim3(Bsz * Hh / 256), dim3(256), 0, stream>>>(
            gbuf, c1, a2h, a2l, K2, 0, a1h, a1l, K1, Em);
        attn_fused<<<dim3(Bsz), dim3(256), 0, stream>>>(
            att_f, a2h, a2l, WahT, wa2, ba2, f_att, a2h, a2l);
        // g2 = A2 @ W2p^T + bih2 + bhh2   (512 x 2048, K=1536)
        gemm_sp<64, 64, 32, false, false, 4><<<dim3(256), 256, 0, stream>>>(
            nullptr, a2h, a2l, K2, w2ph, w2pl, K2, gbuf, 2048, 2048, K2, bih2, bhh2, nullptr, 32);
        lstm_cell_kernel<<<dim3(Bsz * Hh / 256), dim3(256), 0, stream>>>(
            gbuf, c2, a2h, a2l, K2, 1024, nullptr, nullptr, 0, 0);
        // logits = h2 @ Wo^T + bo   (512 x 10000, K=512; 8x79 tiles, MFAST)
        gemm_sp<64, 128, 32, false, false, 3><<<dim3(632), 256, 0, stream>>>(
            nullptr, a2h + 1024, a2l + 1024, K2, woh, wol, 512, logits, Vv, Vv, 512, bo, nullptr, nullptr, 79);
        argmax_embed_kernel<<<dim3(Bsz), dim3(256), 0, stream>>>(logits, E, a1h, a1l, out, t);
    }
}